// Round 10
// baseline (124.704 us; speedup 1.0000x reference)
//
#include <hip/hip_runtime.h>
#include <hip/hip_bf16.h>
#include <stdint.h>

// SketchConv2d: out = conv2d(x, Weff) + bias, where
// Weff[o,f] = (1/4) * sum_{n,s} sketches[n,f,s] * signed[n,s,o]
// f channel-major flat (c*9 + kh*3 + kw).
//
// B=32, CIN=128, H=W=64, OUT=256, KH=KW=3, H2=W2=62, NSK=4, SDIM=128.
//
// Round 10: TWO BLOCKS PER CU (the m114 implicit-overlap mechanism).
//  r4-r9 all serialized LDS-read and MFMA phases at the CU level because the
//  single resident block's barrier locks all 8 waves together. Fix: 80 KB
//  blocks, 2/CU; one block's MFMAs cover the other's read/stage/drain.
//  - block = 256 thr / 4 waves = 256 o x 64 e (ONE i-row);
//    wave = 64 o x 64 e (acc 64 f32).
//  - A: 36 BK=32 fragment-linear images (r9 ws layout, weff unchanged),
//    16 KB double-buffered, global_load_lds, r7-proven 2-phase schedule.
//  - B: 3 x-rows [j 64][c 128] bf16 XOR-swizzled (48 KB), staged once.
//  LDS = 32 + 48 = 80 KB. Grid = 32 b x 62 i = 1984 (8x248 XCD swizzle).

#define BATCH 32
#define CIN   128
#define HH    64
#define WW    64
#define OUTC  256
#define H2    62
#define W2    62
#define A_TILE 16384                  // 256 o x 32 k x 2B per BK=32 step
#define WS_A_BYTES (36 * A_TILE)      // 576 KB
#define BROWB 16384                   // 64 j * 256 B per x-row

typedef __bf16 bf16x8 __attribute__((ext_vector_type(8)));
typedef float  f32x4  __attribute__((ext_vector_type(4)));

typedef unsigned int u32_as1 __attribute__((address_space(1)));
typedef unsigned int u32_as3 __attribute__((address_space(3)));

__device__ __forceinline__ void async_copy16(const void* g, void* l) {
  __builtin_amdgcn_global_load_lds((const u32_as1*)g, (u32_as3*)l, 16, 0, 0);
}

// ---------------------------------------------------------------------------
// Kernel 1 (unchanged from r9, verified): Weff -> 36 fragment-linear images.
// st = tap*4 + (c>>5), tap = kh*3+kw, kk = c&31:
// byte = st*16384 + (o>>4)*1024 + ((kk>>3)*16 + (o&15))*16 + (kk&7)*2
// ---------------------------------------------------------------------------
#define FPB 4
__global__ __launch_bounds__(256) void weff_kernel(
    const float* __restrict__ sketches,   // (4, 1152, 128)
    const float* __restrict__ sgn,        // (4, 128, 256)
    char* __restrict__ wsA)
{
  __shared__ alignas(16) float sk[512 * FPB];
  const int f0 = blockIdx.x * FPB;
  const int t  = threadIdx.x;

  for (int k = 0; k < (512 * FPB) / 256; ++k) {
    int idx = t + k * 256;
    int fi  = idx >> 9;
    int ns  = idx & 511;
    int n   = ns >> 7;
    int s   = ns & 127;
    sk[ns * FPB + fi] = sketches[(n * 1152 + f0 + fi) * 128 + s];
  }
  __syncthreads();

  const int o = t;
  float acc0 = 0.f, acc1 = 0.f, acc2 = 0.f, acc3 = 0.f;
#pragma unroll 8
  for (int ns = 0; ns < 512; ++ns) {
    float sg = sgn[ns * 256 + o];
    f32x4 skv = *(const f32x4*)(&sk[ns * FPB]);
    acc0 += sg * skv[0];
    acc1 += sg * skv[1];
    acc2 += sg * skv[2];
    acc3 += sg * skv[3];
  }

  float accs[FPB] = {acc0, acc1, acc2, acc3};
#pragma unroll
  for (int fi = 0; fi < FPB; ++fi) {
    int f   = f0 + fi;
    int c   = f / 9;
    int tap = f - c * 9;
    int st  = tap * 4 + (c >> 5);
    int kk  = c & 31;
    uint32_t byteoff = (uint32_t)st * A_TILE + (uint32_t)(o >> 4) * 1024
                     + (uint32_t)(((kk >> 3) * 16 + (o & 15)) * 16)
                     + (uint32_t)((kk & 7) * 2);
    *(__hip_bfloat16*)(wsA + byteoff) = __float2bfloat16(accs[fi] * 0.25f);
  }
}

// ---------------------------------------------------------------------------
// Kernel 2: implicit-GEMM conv, 80 KB block, 2 blocks/CU.
// Block (b, i): 256 o x 64 e, 4 waves; wave w = o-quarter (64 o's).
// ---------------------------------------------------------------------------
__global__ __launch_bounds__(256, 2) void conv_kernel(
    const float* __restrict__ x,
    const char*  __restrict__ wA,
    const float* __restrict__ bias,
    float* __restrict__ out)
{
  __shared__ alignas(16) char lds[2 * A_TILE + 3 * BROWB];  // 32 + 48 KB
  char* ldsA = lds;
  char* ldsB = lds + 2 * A_TILE;

  const int bid = blockIdx.x;
  const int swz = (bid & 7) * 248 + (bid >> 3);   // 1984 = 8*248, bijective
  const int b   = swz / H2;
  const int i   = swz - b * H2;

  const int t    = threadIdx.x;
  const int lane = t & 63;
  const int w    = t >> 6;       // 0..3 = o-quarter

  // stage one 16 KB A image: 4 x 1KB glds per wave (linear)
#define STAGE_A(ST, BUF) do {                                              \
    const char* asrc_ = wA + (size_t)(ST) * A_TILE + w * 4096 + lane * 16; \
    char* adst_ = ldsA + (BUF) * A_TILE + w * 4096;                        \
    async_copy16(asrc_,         adst_);                                    \
    async_copy16(asrc_ + 1024,  adst_ + 1024);                             \
    async_copy16(asrc_ + 2048,  adst_ + 2048);                             \
    async_copy16(asrc_ + 3072,  adst_ + 3072);                             \
  } while (0)

  STAGE_A(0, 0);   // in flight across the whole B staging

  // ---- stage B once: x[b, :, i..i+2, :] -> bf16 LDS [r][j][c], swizzled
  // (i <= 61 so i+2 <= 63: no row clamp needed)
  {
    const int j  = t & 63;
    const int cq = t >> 6;                         // 4 groups of 32 channels
    const uint32_t swb = (uint32_t)((j & 7) << 4);
#pragma unroll
    for (int r = 0; r < 3; ++r) {
      const float* xr = x + (((size_t)(b * CIN + cq * 32)) * HH + (i + r)) * WW + j;
      char* lrow = ldsB + r * BROWB + j * 256;
#pragma unroll
      for (int g = 0; g < 4; ++g) {
        bf16x8 pk;
#pragma unroll
        for (int cc = 0; cc < 8; ++cc)
          pk[cc] = (__bf16)xr[(size_t)(g * 8 + cc) * (HH * WW)];
        uint32_t c0b = (uint32_t)(cq * 64 + g * 16);
        *(bf16x8*)(lrow + (c0b ^ swb)) = pk;
      }
    }
  }

  f32x4 acc[4][4];
  const f32x4 zf = {0.f, 0.f, 0.f, 0.f};
#pragma unroll
  for (int mi = 0; mi < 4; ++mi)
#pragma unroll
    for (int ni = 0; ni < 4; ++ni)
      acc[mi][ni] = zf;

  // ---- per-lane LDS read bases
  const int ln15  = lane & 15;
  const int khi16 = (lane >> 4) << 4;              // byte of 8-elem k-group
  // A fragment-linear: frag (w, mi) at w*4096 + mi*1024 + lane*16
  const char* pA = ldsA + w * 4096 + lane * 16;

  // B: element c at row col: byte = col*256 + ((c*2) ^ ((col&7)<<4)).
  // Split c*2 = CK2*128 + PAR*64 + khi16 (CK2 = ck>>1 imm-safe bit 7;
  // PAR = ck&1 inside the XOR via pointer family).
#define MKB(COL, PAR) (ldsB + (COL) * 256                                  \
    + (uint32_t)((((PAR) * 64) | khi16) ^ (((COL) & 7) << 4)))
  const char* pB00 = MKB(ln15 + 0, 0); const char* pB01 = MKB(ln15 + 0, 1);
  const char* pB10 = MKB(ln15 + 1, 0); const char* pB11 = MKB(ln15 + 1, 1);
  const char* pB20 = MKB(ln15 + 2, 0); const char* pB21 = MKB(ln15 + 2, 1);
  const int c30 = (48 + ln15 + 0 > 63) ? 63 : 48 + ln15 + 0;
  const int c31 = (48 + ln15 + 1 > 63) ? 63 : 48 + ln15 + 1;
  const int c32 = (48 + ln15 + 2 > 63) ? 63 : 48 + ln15 + 2;
  const char* pC00 = MKB(c30, 0); const char* pC01 = MKB(c30, 1);
  const char* pC10 = MKB(c31, 0); const char* pC11 = MKB(c31, 1);
  const char* pC20 = MKB(c32, 0); const char* pC21 = MKB(c32, 1);
#undef MKB

  __syncthreads();   // drains STAGE_A(0) (vmcnt) + B ds_writes (lgkm)

#define MFMA_ __builtin_amdgcn_mfma_f32_16x16x32_bf16

  // one BK=32 step: stage(s+1) at top (full step of flight), 8 ds_reads +
  // 16 MFMA, __syncthreads (publish stage(s+1), WAR for buf (s+1)&1).
  // The co-resident second block covers the drain (m114 TLP).
#define STEP(ST, KH, KW, CK2, PAR) do {                                    \
    if ((ST) < 35) STAGE_A((ST) + 1, ((ST) + 1) & 1);                      \
    const int ab_ = ((ST) & 1) * A_TILE;                                   \
    const int bi_ = (KH) * BROWB + (CK2) * 128;                            \
    bf16x8 b0_ = *(const bf16x8*)(pB##KW##PAR + bi_);                      \
    bf16x8 b1_ = *(const bf16x8*)(pB##KW##PAR + bi_ + 4096);               \
    bf16x8 b2_ = *(const bf16x8*)(pB##KW##PAR + bi_ + 8192);               \
    bf16x8 b3_ = *(const bf16x8*)(pC##KW##PAR + bi_);                      \
    bf16x8 a0_ = *(const bf16x8*)(pA + ab_);                               \
    bf16x8 a1_ = *(const bf16x8*)(pA + ab_ + 1024);                        \
    bf16x8 a2_ = *(const bf16x8*)(pA + ab_ + 2048);                        \
    bf16x8 a3_ = *(const bf16x8*)(pA + ab_ + 3072);                        \
    __builtin_amdgcn_s_setprio(1);                                         \
    acc[0][0] = MFMA_(a0_, b0_, acc[0][0], 0, 0, 0);                       \
    acc[0][1] = MFMA_(a0_, b1_, acc[0][1], 0, 0, 0);                       \
    acc[0][2] = MFMA_(a0_, b2_, acc[0][2], 0, 0, 0);                       \
    acc[0][3] = MFMA_(a0_, b3_, acc[0][3], 0, 0, 0);                       \
    acc[1][0] = MFMA_(a1_, b0_, acc[1][0], 0, 0, 0);                       \
    acc[1][1] = MFMA_(a1_, b1_, acc[1][1], 0, 0, 0);                       \
    acc[1][2] = MFMA_(a1_, b2_, acc[1][2], 0, 0, 0);                       \
    acc[1][3] = MFMA_(a1_, b3_, acc[1][3], 0, 0, 0);                       \
    acc[2][0] = MFMA_(a2_, b0_, acc[2][0], 0, 0, 0);                       \
    acc[2][1] = MFMA_(a2_, b1_, acc[2][1], 0, 0, 0);                       \
    acc[2][2] = MFMA_(a2_, b2_, acc[2][2], 0, 0, 0);                       \
    acc[2][3] = MFMA_(a2_, b3_, acc[2][3], 0, 0, 0);                       \
    acc[3][0] = MFMA_(a3_, b0_, acc[3][0], 0, 0, 0);                       \
    acc[3][1] = MFMA_(a3_, b1_, acc[3][1], 0, 0, 0);                       \
    acc[3][2] = MFMA_(a3_, b2_, acc[3][2], 0, 0, 0);                       \
    acc[3][3] = MFMA_(a3_, b3_, acc[3][3], 0, 0, 0);                       \
    __builtin_amdgcn_s_setprio(0);                                         \
    if ((ST) < 35) __syncthreads();                                        \
  } while (0)

  STEP(0,  0, 0, 0, 0);  STEP(1,  0, 0, 0, 1);
  STEP(2,  0, 0, 1, 0);  STEP(3,  0, 0, 1, 1);
  STEP(4,  0, 1, 0, 0);  STEP(5,  0, 1, 0, 1);
  STEP(6,  0, 1, 1, 0);  STEP(7,  0, 1, 1, 1);
  STEP(8,  0, 2, 0, 0);  STEP(9,  0, 2, 0, 1);
  STEP(10, 0, 2, 1, 0);  STEP(11, 0, 2, 1, 1);
  STEP(12, 1, 0, 0, 0);  STEP(13, 1, 0, 0, 1);
  STEP(14, 1, 0, 1, 0);  STEP(15, 1, 0, 1, 1);
  STEP(16, 1, 1, 0, 0);  STEP(17, 1, 1, 0, 1);
  STEP(18, 1, 1, 1, 0);  STEP(19, 1, 1, 1, 1);
  STEP(20, 1, 2, 0, 0);  STEP(21, 1, 2, 0, 1);
  STEP(22, 1, 2, 1, 0);  STEP(23, 1, 2, 1, 1);
  STEP(24, 2, 0, 0, 0);  STEP(25, 2, 0, 0, 1);
  STEP(26, 2, 0, 1, 0);  STEP(27, 2, 0, 1, 1);
  STEP(28, 2, 1, 0, 0);  STEP(29, 2, 1, 0, 1);
  STEP(30, 2, 1, 1, 0);  STEP(31, 2, 1, 1, 1);
  STEP(32, 2, 2, 0, 0);  STEP(33, 2, 2, 0, 1);
  STEP(34, 2, 2, 1, 0);  STEP(35, 2, 2, 1, 1);

#undef STEP
#undef MFMA_
#undef STAGE_A

  // ---- epilogue: D[m][n]: m=(lane>>4)*4+reg, n=lane&15
  const int jn = ln15;
  const int g4 = lane >> 4;
#pragma unroll
  for (int mi = 0; mi < 4; ++mi) {
#pragma unroll
    for (int ni = 0; ni < 4; ++ni) {
      const int jj = (ni << 4) + jn;
      if (jj < W2) {
#pragma unroll
        for (int rr = 0; rr < 4; ++rr) {
          const int o = (w << 6) + (mi << 4) + (g4 << 2) + rr;
          out[(((size_t)b * OUTC + o) * H2 + i) * W2 + jj] =
              acc[mi][ni][rr] + bias[o];
        }
      }
    }
  }
}

extern "C" void kernel_launch(void* const* d_in, const int* in_sizes, int n_in,
                              void* d_out, int out_size, void* d_ws, size_t ws_size,
                              hipStream_t stream) {
  const float* x        = (const float*)d_in[0];
  const float* sketches = (const float*)d_in[1];
  const float* sgn      = (const float*)d_in[2];
  const float* bias     = (const float*)d_in[3];
  float* out            = (float*)d_out;
  char* wsA             = (char*)d_ws;

  if (ws_size < (size_t)WS_A_BYTES) return;  // need 576 KB scratch

  weff_kernel<<<1152 / FPB, 256, 0, stream>>>(sketches, sgn, wsA);
  conv_kernel<<<BATCH * H2, 256, 0, stream>>>(x, wsA, bias, out);
}

// Round 11
// 105.329 us; speedup vs baseline: 1.1839x; 1.1839x over previous
//
#include <hip/hip_runtime.h>
#include <hip/hip_bf16.h>
#include <stdint.h>

// SketchConv2d: out = conv2d(x, Weff) + bias, where
// Weff[o,f] = (1/4) * sum_{n,s} sketches[n,f,s] * signed[n,s,o]
// f channel-major flat (c*9 + kh*3 + kw).
//
// B=32, CIN=128, H=W=64, OUT=256, KH=KW=3, H2=W2=62, NSK=4, SDIM=128.
//
// Round 11: m201 8-phase-template port (T2+T3+T4+T5), loop-ified.
//  - 36 BK=32 K-steps, A ring 4 x 16 KB (glds-staged, fragment-linear
//    images from ws), B 6 x-rows resident (96 KB). LDS = 160 KB.
//  - per step: vmcnt(2); s_barrier; STAGE(s+3, clamped); lgkm0; 16 MFMA
//    (operands prefetched previous phase); read mi4-7; s_barrier; lgkm0;
//    16 MFMA; trailing reads for step s+1. vmcnt never drains mid-loop.
//  - outer loop kh=0..2 (#pragma unroll 1): body ~8 KB, I$-resident
//    (previous rounds fully unrolled ~40 KB straight-line).

#define BATCH 32
#define CIN   128
#define HH    64
#define WW    64
#define OUTC  256
#define H2    62
#define W2    62
#define A_TILE 16384                  // 256 o x 32 k x 2B per BK=32 step
#define WS_A_BYTES (36 * A_TILE)      // 576 KB
#define BROWB 16384                   // 64 j * 256 B per x-row
#define AMAX  (35 * A_TILE)

typedef __bf16 bf16x8 __attribute__((ext_vector_type(8)));
typedef float  f32x4  __attribute__((ext_vector_type(4)));

typedef unsigned int u32_as1 __attribute__((address_space(1)));
typedef unsigned int u32_as3 __attribute__((address_space(3)));

__device__ __forceinline__ void async_copy16(const void* g, void* l) {
  __builtin_amdgcn_global_load_lds((const u32_as1*)g, (u32_as3*)l, 16, 0, 0);
}

// ---------------------------------------------------------------------------
// Kernel 1 (unchanged, verified r9/r10): Weff -> 36 fragment-linear images.
// st = tap*4 + (c>>5), tap = kh*3+kw, kk = c&31:
// byte = st*16384 + (o>>4)*1024 + ((kk>>3)*16 + (o&15))*16 + (kk&7)*2
// ---------------------------------------------------------------------------
#define FPB 4
__global__ __launch_bounds__(256) void weff_kernel(
    const float* __restrict__ sketches,   // (4, 1152, 128)
    const float* __restrict__ sgn,        // (4, 128, 256)
    char* __restrict__ wsA)
{
  __shared__ alignas(16) float sk[512 * FPB];
  const int f0 = blockIdx.x * FPB;
  const int t  = threadIdx.x;

  for (int k = 0; k < (512 * FPB) / 256; ++k) {
    int idx = t + k * 256;
    int fi  = idx >> 9;
    int ns  = idx & 511;
    int n   = ns >> 7;
    int s   = ns & 127;
    sk[ns * FPB + fi] = sketches[(n * 1152 + f0 + fi) * 128 + s];
  }
  __syncthreads();

  const int o = t;
  float acc0 = 0.f, acc1 = 0.f, acc2 = 0.f, acc3 = 0.f;
#pragma unroll 8
  for (int ns = 0; ns < 512; ++ns) {
    float sg = sgn[ns * 256 + o];
    f32x4 skv = *(const f32x4*)(&sk[ns * FPB]);
    acc0 += sg * skv[0];
    acc1 += sg * skv[1];
    acc2 += sg * skv[2];
    acc3 += sg * skv[3];
  }

  float accs[FPB] = {acc0, acc1, acc2, acc3};
#pragma unroll
  for (int fi = 0; fi < FPB; ++fi) {
    int f   = f0 + fi;
    int c   = f / 9;
    int tap = f - c * 9;
    int st  = tap * 4 + (c >> 5);
    int kk  = c & 31;
    uint32_t byteoff = (uint32_t)st * A_TILE + (uint32_t)(o >> 4) * 1024
                     + (uint32_t)(((kk >> 3) * 16 + (o & 15)) * 16)
                     + (uint32_t)((kk & 7) * 2);
    *(__hip_bfloat16*)(wsA + byteoff) = __float2bfloat16(accs[fi] * 0.25f);
  }
}

// ---------------------------------------------------------------------------
// Kernel 2: implicit-GEMM conv, m201-style phased pipeline, looped.
// Block (b, ig): 256 o x 256 e (4 i-rows x 64 j), 8 waves (512 thr).
// wave: wm = w>>2 (o-half of 128 rows), we = w&3 (i-row).
// ---------------------------------------------------------------------------
__global__ __launch_bounds__(512, 2) void conv_kernel(
    const float* __restrict__ x,
    const char*  __restrict__ wA,
    const float* __restrict__ bias,
    float* __restrict__ out)
{
  __shared__ alignas(16) char lds[4 * A_TILE + 6 * BROWB];  // 64 + 96 KB
  char* ldsA = lds;
  char* ldsB = lds + 4 * A_TILE;

  const int bid = blockIdx.x;
  const int swz = (bid & 7) * 64 + (bid >> 3);    // 512 = 8*64, bijective
  const int b   = swz >> 4;
  const int ig  = swz & 15;
  const int i0  = ig * 4;

  const int t    = threadIdx.x;
  const int lane = t & 63;
  const int w    = t >> 6;       // 0..7
  const int wm   = w >> 2;       // o-half (128 rows)
  const int we   = w & 3;        // i-row within group

  const char* aSrcLane = wA + w * 2048 + lane * 16;

#define STAGE(AOFF, TGT) do {                                              \
    const char* s_ = aSrcLane + (AOFF);                                    \
    char* d_ = ldsA + (TGT) * A_TILE + w * 2048;                           \
    async_copy16(s_,        d_);                                           \
    async_copy16(s_ + 1024, d_ + 1024);                                    \
  } while (0)

  // prologue: tiles 0..2 in flight across B staging
  STAGE(0, 0);
  STAGE(A_TILE, 1);
  STAGE(2 * A_TILE, 2);

  // ---- stage B once: x[b, :, i0..i0+5 (row-clamped), :] -> [r][j][c] swz
  {
    const int j  = t & 63;
    const int cq = t >> 6;                         // 8 groups of 16 channels
    const uint32_t swb = (uint32_t)((j & 7) << 4);
#pragma unroll
    for (int r = 0; r < 6; ++r) {
      int xrow = i0 + r; if (xrow > 63) xrow = 63;
      const float* xr = x + (((size_t)(b * CIN + cq * 16)) * HH + xrow) * WW + j;
      char* lrow = ldsB + r * BROWB + j * 256;
#pragma unroll
      for (int g = 0; g < 2; ++g) {
        bf16x8 pk;
#pragma unroll
        for (int cc = 0; cc < 8; ++cc)
          pk[cc] = (__bf16)xr[(size_t)(g * 8 + cc) * (HH * WW)];
        uint32_t c0b = (uint32_t)(cq * 32 + g * 16);
        *(bf16x8*)(lrow + (c0b ^ swb)) = pk;
      }
    }
  }

  f32x4 acc[8][4];
  const f32x4 zf = {0.f, 0.f, 0.f, 0.f};
#pragma unroll
  for (int mi = 0; mi < 8; ++mi)
#pragma unroll
    for (int ni = 0; ni < 4; ++ni)
      acc[mi][ni] = zf;

  // ---- per-lane LDS read bases
  const int ln15  = lane & 15;
  const int khi16 = (lane >> 4) << 4;
  const char* pA = ldsA + wm * 8192 + lane * 16;   // frag mi at +mi*1024

#define MKB(COL, PAR) (ldsB + we * BROWB + (COL) * 256                     \
    + (uint32_t)(((((PAR) * 64) | khi16) ^ (((COL) & 7) << 4))))
  const char* pB00 = MKB(ln15 + 0, 0); const char* pB01 = MKB(ln15 + 0, 1);
  const char* pB10 = MKB(ln15 + 1, 0); const char* pB11 = MKB(ln15 + 1, 1);
  const char* pB20 = MKB(ln15 + 2, 0); const char* pB21 = MKB(ln15 + 2, 1);
  const int c30 = (48 + ln15 + 0 > 63) ? 63 : 48 + ln15 + 0;
  const int c31 = (48 + ln15 + 1 > 63) ? 63 : 48 + ln15 + 1;
  const int c32 = (48 + ln15 + 2 > 63) ? 63 : 48 + ln15 + 2;
  const char* pC00 = MKB(c30, 0); const char* pC01 = MKB(c30, 1);
  const char* pC10 = MKB(c31, 0); const char* pC11 = MKB(c31, 1);
  const char* pC20 = MKB(c32, 0); const char* pC21 = MKB(c32, 1);
#undef MKB

  __syncthreads();   // drains tiles 0-2 (vmcnt0) + all B ds_writes, publishes

  bf16x8 aX0, aX1, aX2, aX3, aY0, aY1, aY2, aY3, b0, b1, b2, b3;

  // initial operands: step 0 (buf 0, kw=0, ck2=0, par=0)
  aX0 = *(const bf16x8*)(pA);
  aX1 = *(const bf16x8*)(pA + 1024);
  aX2 = *(const bf16x8*)(pA + 2048);
  aX3 = *(const bf16x8*)(pA + 3072);
  b0  = *(const bf16x8*)(pB00);
  b1  = *(const bf16x8*)(pB00 + 4096);
  b2  = *(const bf16x8*)(pB00 + 8192);
  b3  = *(const bf16x8*)(pC00);

  uint32_t aoff = 3 * A_TILE;    // next tile to stage

#define MFMA_ __builtin_amdgcn_mfma_f32_16x16x32_bf16
#define LGKM0 asm volatile("s_waitcnt lgkmcnt(0)" ::: "memory")
#define VM2   asm volatile("s_waitcnt vmcnt(2)" ::: "memory")

#define MFMA16(A0_, A1_, A2_, A3_, M_) do {                                \
    __builtin_amdgcn_s_setprio(1);                                         \
    acc[(M_)+0][0] = MFMA_(A0_, b0, acc[(M_)+0][0], 0, 0, 0);              \
    acc[(M_)+0][1] = MFMA_(A0_, b1, acc[(M_)+0][1], 0, 0, 0);              \
    acc[(M_)+0][2] = MFMA_(A0_, b2, acc[(M_)+0][2], 0, 0, 0);              \
    acc[(M_)+0][3] = MFMA_(A0_, b3, acc[(M_)+0][3], 0, 0, 0);              \
    acc[(M_)+1][0] = MFMA_(A1_, b0, acc[(M_)+1][0], 0, 0, 0);              \
    acc[(M_)+1][1] = MFMA_(A1_, b1, acc[(M_)+1][1], 0, 0, 0);              \
    acc[(M_)+1][2] = MFMA_(A1_, b2, acc[(M_)+1][2], 0, 0, 0);              \
    acc[(M_)+1][3] = MFMA_(A1_, b3, acc[(M_)+1][3], 0, 0, 0);              \
    acc[(M_)+2][0] = MFMA_(A2_, b0, acc[(M_)+2][0], 0, 0, 0);              \
    acc[(M_)+2][1] = MFMA_(A2_, b1, acc[(M_)+2][1], 0, 0, 0);              \
    acc[(M_)+2][2] = MFMA_(A2_, b2, acc[(M_)+2][2], 0, 0, 0);              \
    acc[(M_)+2][3] = MFMA_(A2_, b3, acc[(M_)+2][3], 0, 0, 0);              \
    acc[(M_)+3][0] = MFMA_(A3_, b0, acc[(M_)+3][0], 0, 0, 0);              \
    acc[(M_)+3][1] = MFMA_(A3_, b1, acc[(M_)+3][1], 0, 0, 0);              \
    acc[(M_)+3][2] = MFMA_(A3_, b2, acc[(M_)+3][2], 0, 0, 0);              \
    acc[(M_)+3][3] = MFMA_(A3_, b3, acc[(M_)+3][3], 0, 0, 0);              \
    __builtin_amdgcn_s_setprio(0);                                         \
  } while (0)

  // one BK=32 step at body position Q (static). Trailing reads fetch step
  // s+1 operands (tile s+1 published by THIS step's vmcnt(2)+barrier).
  // KWN/PARN/CK2N = step s+1 B params; (Q+1)&3 = its A buffer.
#define STEPQ(Q, KWN, PARN, CK2N) do {                                     \
    VM2;                                                                   \
    __builtin_amdgcn_s_barrier();                                          \
    STAGE(aoff, (Q + 3) & 3);                                              \
    aoff += A_TILE; if (aoff > AMAX) aoff = AMAX;                          \
    LGKM0;                                                                 \
    MFMA16(aX0, aX1, aX2, aX3, 0);                                         \
    aY0 = *(const bf16x8*)(pA + (Q & 3) * A_TILE + 4096);                  \
    aY1 = *(const bf16x8*)(pA + (Q & 3) * A_TILE + 5120);                  \
    aY2 = *(const bf16x8*)(pA + (Q & 3) * A_TILE + 6144);                  \
    aY3 = *(const bf16x8*)(pA + (Q & 3) * A_TILE + 7168);                  \
    __builtin_amdgcn_s_barrier();                                          \
    LGKM0;                                                                 \
    MFMA16(aY0, aY1, aY2, aY3, 4);                                         \
    aX0 = *(const bf16x8*)(pA + ((Q + 1) & 3) * A_TILE);                   \
    aX1 = *(const bf16x8*)(pA + ((Q + 1) & 3) * A_TILE + 1024);            \
    aX2 = *(const bf16x8*)(pA + ((Q + 1) & 3) * A_TILE + 2048);            \
    aX3 = *(const bf16x8*)(pA + ((Q + 1) & 3) * A_TILE + 3072);            \
    b0 = *(const bf16x8*)(pB##KWN##PARN + (CK2N) * 128);                   \
    b1 = *(const bf16x8*)(pB##KWN##PARN + (CK2N) * 128 + 4096);            \
    b2 = *(const bf16x8*)(pB##KWN##PARN + (CK2N) * 128 + 8192);            \
    b3 = *(const bf16x8*)(pC##KWN##PARN + (CK2N) * 128);                   \
  } while (0)

#pragma unroll 1
  for (int kh = 0; kh < 3; ++kh) {
    STEPQ(0, 0, 1, 0);
    STEPQ(1, 0, 0, 1);
    STEPQ(2, 0, 1, 1);
    STEPQ(3, 1, 0, 0);
    STEPQ(4, 1, 1, 0);
    STEPQ(5, 1, 0, 1);
    STEPQ(6, 1, 1, 1);
    STEPQ(7, 2, 0, 0);
    STEPQ(8, 2, 1, 0);
    STEPQ(9, 2, 0, 1);
    STEPQ(10, 2, 1, 1);
    // Q=11: bump B pointers to next kh BEFORE trailing reads (step s+1 =
    // next iteration's q=0). Last iteration: no bump; trailing reads are
    // dead (no step 36) and read valid stale addresses.
    {
      VM2;
      __builtin_amdgcn_s_barrier();
      STAGE(aoff, (11 + 3) & 3);
      aoff += A_TILE; if (aoff > AMAX) aoff = AMAX;
      LGKM0;
      MFMA16(aX0, aX1, aX2, aX3, 0);
      aY0 = *(const bf16x8*)(pA + (11 & 3) * A_TILE + 4096);
      aY1 = *(const bf16x8*)(pA + (11 & 3) * A_TILE + 5120);
      aY2 = *(const bf16x8*)(pA + (11 & 3) * A_TILE + 6144);
      aY3 = *(const bf16x8*)(pA + (11 & 3) * A_TILE + 7168);
      __builtin_amdgcn_s_barrier();
      LGKM0;
      MFMA16(aY0, aY1, aY2, aY3, 4);
      if (kh < 2) {
        pB00 += BROWB; pB01 += BROWB; pB10 += BROWB; pB11 += BROWB;
        pB20 += BROWB; pB21 += BROWB; pC00 += BROWB; pC01 += BROWB;
        pC10 += BROWB; pC11 += BROWB; pC20 += BROWB; pC21 += BROWB;
      }
      aX0 = *(const bf16x8*)(pA);
      aX1 = *(const bf16x8*)(pA + 1024);
      aX2 = *(const bf16x8*)(pA + 2048);
      aX3 = *(const bf16x8*)(pA + 3072);
      b0 = *(const bf16x8*)(pB00);
      b1 = *(const bf16x8*)(pB00 + 4096);
      b2 = *(const bf16x8*)(pB00 + 8192);
      b3 = *(const bf16x8*)(pC00);
    }
  }

#undef STEPQ
#undef MFMA16
#undef VM2
#undef LGKM0
#undef MFMA_
#undef STAGE

  // ---- epilogue: D[m][n]: m=(lane>>4)*4+reg, n=lane&15
  const int jn   = ln15;
  const int g4   = lane >> 4;
  const int irow = i0 + we;
  if (irow < H2) {
#pragma unroll
    for (int mi = 0; mi < 8; ++mi) {
#pragma unroll
      for (int ni = 0; ni < 4; ++ni) {
        const int jj = (ni << 4) + jn;
        if (jj < W2) {
#pragma unroll
          for (int rr = 0; rr < 4; ++rr) {
            const int o = (wm << 7) + (mi << 4) + (g4 << 2) + rr;
            out[(((size_t)b * OUTC + o) * H2 + irow) * W2 + jj] =
                acc[mi][ni][rr] + bias[o];
          }
        }
      }
    }
  }
}

extern "C" void kernel_launch(void* const* d_in, const int* in_sizes, int n_in,
                              void* d_out, int out_size, void* d_ws, size_t ws_size,
                              hipStream_t stream) {
  const float* x        = (const float*)d_in[0];
  const float* sketches = (const float*)d_in[1];
  const float* sgn      = (const float*)d_in[2];
  const float* bias     = (const float*)d_in[3];
  float* out            = (float*)d_out;
  char* wsA             = (char*)d_ws;

  if (ws_size < (size_t)WS_A_BYTES) return;  // need 576 KB scratch

  weff_kernel<<<1152 / FPB, 256, 0, stream>>>(sketches, sgn, wsA);
  conv_kernel<<<BATCH * 16, 512, 0, stream>>>(x, wsA, bias, out);
}